// Round 15
// baseline (71.574 us; speedup 1.0000x reference)
//
#include <hip/hip_runtime.h>

#define N_SP 16384
#define C_DIM 128
#define K_DIM 32
#define TILEN 32
#define NBP   64     // partial blocks per batch; each block (2 waves) covers 256 n

typedef short short8 __attribute__((ext_vector_type(8)));
typedef float f32x16 __attribute__((ext_vector_type(16)));

__device__ __forceinline__ unsigned f2bfu(float f){
    return (__float_as_uint(f) + 0x8000u) >> 16;   // cheap RN to bf16 bits
}
__device__ __forceinline__ unsigned short f2bf(float f){
    return (unsigned short)f2bfu(f);
}
__device__ __forceinline__ float bf2f(unsigned u){
    return __uint_as_float(u << 16);
}

// XOR-swizzled index into a [row][32] ushort tile: flips n bits 3..4 by row&3
// -> 8-u16 (16B) chunks stay contiguous & aligned; rows spread across banks
#define SWZ(row, n) (((row) << 5) + ((n) ^ (((row) & 3) << 3)))

union FragU { int i[4]; short8 s; };

__global__ __launch_bounds__(128) void enc_main(
    const float* __restrict__ x,       // [B][C][N]
    const float* __restrict__ cw,      // [K][C] fp32
    const float* __restrict__ scale,   // [K]
    unsigned short* __restrict__ wxp,  // [32*NBP][K][C] bf16 block partials
    float* __restrict__ wsp)           // [32*NBP][K]    fp32 block partials
{
    // 20 KB: per-wave slice = xs (8 KB) + aws (2 KB); epilogue aliases all as f32
    __shared__ unsigned short sh[2 * (C_DIM + K_DIM) * TILEN];

    const int t   = threadIdx.x;   // 0..127 (2 waves)
    const int w   = t >> 6;        // wave id
    const int l   = t & 63;
    const int r   = blockIdx.x;    // 0..NBP-1
    const int b   = blockIdx.y;
    const int hi  = (t >> 5) & 1;
    const int l31 = t & 31;

    unsigned short* xs  = sh + w * ((C_DIM + K_DIM) * TILEN);
    unsigned short* aws = xs + C_DIM * TILEN;

    const int nbase = r * 256 + w * 128;   // wave-private 128-n span (4 tiles)

    const float* xb = x + (size_t)b * C_DIM * N_SP + (size_t)(hi * 64) * N_SP;

    // ---- prologue: self-compute cwA, combo (per wave, own LDS slice) ----
    const float s_k = scale[l31];
    const float m2s = -2.f * s_k;
    float c2p = 0.f;
    short8 cwA[8];
#pragma unroll
    for (int ksg = 0; ksg < 8; ++ksg){
        const float* cp = cw + l31 * C_DIM + ksg * 16 + hi * 8;
        float4 a  = *(const float4*)cp;
        float4 b4 = *(const float4*)(cp + 4);
        c2p = fmaf(a.x, a.x, c2p);  c2p = fmaf(a.y, a.y, c2p);
        c2p = fmaf(a.z, a.z, c2p);  c2p = fmaf(a.w, a.w, c2p);
        c2p = fmaf(b4.x, b4.x, c2p); c2p = fmaf(b4.y, b4.y, c2p);
        c2p = fmaf(b4.z, b4.z, c2p); c2p = fmaf(b4.w, b4.w, c2p);
        FragU f;
        f.i[0] = (int)(f2bfu(m2s * a.x)  | (f2bfu(m2s * a.y)  << 16));
        f.i[1] = (int)(f2bfu(m2s * a.z)  | (f2bfu(m2s * a.w)  << 16));
        f.i[2] = (int)(f2bfu(m2s * b4.x) | (f2bfu(m2s * b4.y) << 16));
        f.i[3] = (int)(f2bfu(m2s * b4.z) | (f2bfu(m2s * b4.w) << 16));
        cwA[ksg] = f.s;
    }
    const float c2 = c2p + __shfl_xor(c2p, 32);   // full ||cw_k||^2, k = l31

    {   // combo broadcast through own aws slice (in-wave ordering suffices)
        float* combof = (float*)aws;
        combof[2 * l31]     = s_k;
        combof[2 * l31 + 1] = s_k * c2;
    }
    float csx[16], csy[16];
#pragma unroll
    for (int q = 0; q < 16; ++q){
        const int row = (q & 3) + 8 * (q >> 2) + 4 * hi;
        const float* combof = (const float*)aws;
        csx[q] = combof[2 * row];
        csy[q] = combof[2 * row + 1];
    }

    f32x16 acc0, acc1, acc2, acc3, accS;
#pragma unroll
    for (int i = 0; i < 16; ++i){
        acc0[i]=0.f; acc1[i]=0.f; acc2[i]=0.f; acc3[i]=0.f; accS[i]=0.f;
    }
    short8 ones;
#pragma unroll
    for (int i = 0; i < 8; ++i) ones[i] = (short)0x3F80;  // bf16 1.0

#pragma unroll 1
    for (int tile = 0; tile < 4; ++tile){
        const int n0 = nbase + tile * TILEN;
        const float* xp = xb + n0 + l31;

        __syncthreads();   // xs/aws safe to overwrite (prev tile's phase-D done)

        f32x16 sA;         // S[k][n] accumulator, cols n = l31
#pragma unroll
        for (int i = 0; i < 16; ++i) sA[i] = 0.f;

        float x2 = 0.f;    // partial ||x||^2 over this thread's 64 c-rows
        int xr[32];        // packed bf16 pairs: xr[m] = rows 2m,2m+1 (local)

        // ---- phase 1: stream 64 c-rows (depth-2, 8-wide), stage bf16 ----
        float cur[8], nx1[8];
#pragma unroll
        for (int j = 0; j < 8; ++j) cur[j] = xp[(size_t)j * N_SP];
#pragma unroll
        for (int j = 0; j < 8; ++j) nx1[j] = xp[(size_t)(8 + j) * N_SP];

#pragma unroll
        for (int g = 0; g < 8; ++g){
            float nx2[8];
            if (g < 6){
#pragma unroll
                for (int j = 0; j < 8; ++j) nx2[j] = xp[(size_t)((g + 2) * 8 + j) * N_SP];
            } else {
#pragma unroll
                for (int j = 0; j < 8; ++j) nx2[j] = 0.f;
            }
#pragma unroll
            for (int j = 0; j < 8; j += 2){
                const int rl = g * 8 + j;        // local row 0..63
                const int c  = hi * 64 + rl;     // global c-row
                const float a0 = cur[j], a1 = cur[j + 1];
                x2 = fmaf(a0, a0, x2);
                x2 = fmaf(a1, a1, x2);
                const unsigned u0 = f2bfu(a0), u1 = f2bfu(a1);
                xs[SWZ(c,     l31)] = (unsigned short)u0;
                xs[SWZ(c + 1, l31)] = (unsigned short)u1;
                xr[rl >> 1] = (int)(u0 | (u1 << 16));
            }
            if (g < 7){
#pragma unroll
                for (int j = 0; j < 8; ++j){ cur[j] = nx1[j]; nx1[j] = nx2[j]; }
            }
        }

        // ---- phase S: S[k][col l31] += cwt2[k][c] * x[c][col], 8 c-steps of 16 ----
        // pair (t, t^32) holds same column, different c-half; exchange via shfl_xor
#pragma unroll
        for (int ks = 0; ks < 8; ++ks){
            FragU f;
            if (ks < 4){
#pragma unroll
                for (int d = 0; d < 4; ++d){
                    const int own = xr[ks * 8 + d];                     // c = ks*16+2d (hi=0)
                    const int oth = __shfl_xor(xr[ks * 8 + 4 + d], 32); // c = ks*16+8+2d
                    f.i[d] = hi ? oth : own;
                }
            } else {
                const int k4 = ks - 4;
#pragma unroll
                for (int d = 0; d < 4; ++d){
                    const int own = xr[k4 * 8 + 4 + d];                 // c = ks*16+8+2d (hi=1)
                    const int oth = __shfl_xor(xr[k4 * 8 + d], 32);     // c = ks*16+2d
                    f.i[d] = hi ? own : oth;
                }
            }
            sA = __builtin_amdgcn_mfma_f32_32x32x16_bf16(cwA[ks], f.s, sA, 0, 0, 0);
        }

        // ---- phase 2: softmax over k (col l31), D-layout ----
        const float x2f = x2 + __shfl_xor(x2, 32);   // full ||x||^2 for col l31
        {
            float arg[16]; float ml = -3.4e38f;
#pragma unroll
            for (int q = 0; q < 16; ++q){
                arg[q] = fmaf(csx[q], x2f, sA[q] + csy[q]);  // scale*(x2-2x.cw+c2)
                ml = fmaxf(ml, arg[q]);
            }
            const float mm = fmaxf(ml, __shfl_xor(ml, 32));
            float sum = 0.f;
#pragma unroll
            for (int q = 0; q < 16; ++q){ float p = __expf(arg[q] - mm); arg[q] = p; sum += p; }
            sum += __shfl_xor(sum, 32);
            const float rr = 1.f / sum;
#pragma unroll
            for (int q = 0; q < 16; ++q){
                const int row = (q & 3) + 8 * (q >> 2) + 4 * hi;
                aws[SWZ(row, l31)] = f2bf(arg[q] * rr);
            }
        }

        __syncthreads();   // aws complete

        // ---- phase D: wx[k][c] += aw[k][n] * x[n][c], 2 n-steps of 16 ----
#pragma unroll
        for (int ks = 0; ks < 2; ++ks){
            const int n8 = ks * 16 + hi * 8;
            short8 af  = *(const short8*)(const void*)&aws[SWZ(l31, n8)];
            short8 bf0 = *(const short8*)(const void*)&xs[SWZ(l31,      n8)];
            short8 bf1 = *(const short8*)(const void*)&xs[SWZ(32 + l31, n8)];
            short8 bf2 = *(const short8*)(const void*)&xs[SWZ(64 + l31, n8)];
            short8 bf3 = *(const short8*)(const void*)&xs[SWZ(96 + l31, n8)];
            acc0 = __builtin_amdgcn_mfma_f32_32x32x16_bf16(af, bf0, acc0, 0, 0, 0);
            acc1 = __builtin_amdgcn_mfma_f32_32x32x16_bf16(af, bf1, acc1, 0, 0, 0);
            acc2 = __builtin_amdgcn_mfma_f32_32x32x16_bf16(af, bf2, acc2, 0, 0, 0);
            acc3 = __builtin_amdgcn_mfma_f32_32x32x16_bf16(af, bf3, acc3, 0, 0, 0);
            accS = __builtin_amdgcn_mfma_f32_32x32x16_bf16(af, ones, accS, 0, 0, 0);
        }
    }

    // ---- epilogue: cross-wave fp32 sum through LDS, then bf16 partial store ----
    __syncthreads();                     // all phase-D LDS reads done (both waves)
    float* fbuf = (float*)sh;            // 5 accs x 16 regs x 64 lanes = 20480 B
    if (w == 1){
#pragma unroll
        for (int rg = 0; rg < 16; ++rg){
            fbuf[(0 * 16 + rg) * 64 + l] = acc0[rg];
            fbuf[(1 * 16 + rg) * 64 + l] = acc1[rg];
            fbuf[(2 * 16 + rg) * 64 + l] = acc2[rg];
            fbuf[(3 * 16 + rg) * 64 + l] = acc3[rg];
            fbuf[(4 * 16 + rg) * 64 + l] = accS[rg];
        }
    }
    __syncthreads();
    if (w == 0){
        const int blk = b * NBP + r;
        unsigned short* wxp_blk = wxp + (size_t)blk * (K_DIM * C_DIM);
#pragma unroll
        for (int rg = 0; rg < 16; ++rg){
            const float a0 = acc0[rg] + fbuf[(0 * 16 + rg) * 64 + l];
            const float a1 = acc1[rg] + fbuf[(1 * 16 + rg) * 64 + l];
            const float a2 = acc2[rg] + fbuf[(2 * 16 + rg) * 64 + l];
            const float a3 = acc3[rg] + fbuf[(3 * 16 + rg) * 64 + l];
            const int row = (rg & 3) + 8 * (rg >> 2) + 4 * hi;  // verified D layout
            wxp_blk[row * C_DIM +      l31] = f2bf(a0);
            wxp_blk[row * C_DIM + 32 + l31] = f2bf(a1);
            wxp_blk[row * C_DIM + 64 + l31] = f2bf(a2);
            wxp_blk[row * C_DIM + 96 + l31] = f2bf(a3);
        }
        if (l31 == 0){
            float* wsp_blk = wsp + (size_t)blk * K_DIM;
#pragma unroll
            for (int rg = 0; rg < 16; ++rg){
                const int row = (rg & 3) + 8 * (rg >> 2) + 4 * hi;
                wsp_blk[row] = accS[rg] + fbuf[(4 * 16 + rg) * 64 + l];
            }
        }
    }
}

// out[b][k][c] = sum_j wxp[b*NBP+j][k][c] - (sum_j wsp[b*NBP+j][k]) * cw[k][c]
__global__ __launch_bounds__(256) void enc_reduce(
    const unsigned short* __restrict__ wxp, const float* __restrict__ wsp,
    const float* __restrict__ cw, float* __restrict__ out)
{
    const int t = threadIdx.x;          // 0..255
    const int k = blockIdx.x & (K_DIM - 1);
    const int b = blockIdx.x >> 5;      // grid = 32*32

    __shared__ float ps[8][C_DIM];
    __shared__ float wsl;

    // wsum: wave 0 (threads 0..63) loads one partial each, full-wave reduce
    if (t < 64){
        float wv = wsp[(size_t)(b * NBP + t) * K_DIM + k];
#pragma unroll
        for (int off = 32; off; off >>= 1) wv += __shfl_down(wv, off);
        if (t == 0) wsl = wv;
    }

    // wx: thread (jg = t>>5, c4 = (t&31)*4) sums NBP/8 = 8 bf16x4 partials
    const int c4 = (t & 31) * 4;
    const int jg = t >> 5;              // 0..7
    float4 s; s.x = 0.f; s.y = 0.f; s.z = 0.f; s.w = 0.f;
    const unsigned short* pp = wxp + ((size_t)(b * NBP) + jg) * (K_DIM * C_DIM) + k * C_DIM + c4;
#pragma unroll
    for (int j = 0; j < NBP; j += 8){   // 8 iterations
        uint2 v = *(const uint2*)(pp + (size_t)j * (K_DIM * C_DIM));
        s.x += bf2f(v.x & 0xFFFFu);
        s.y += bf2f(v.x >> 16);
        s.z += bf2f(v.y & 0xFFFFu);
        s.w += bf2f(v.y >> 16);
    }
    *(float4*)&ps[jg][c4] = s;
    __syncthreads();

    if (t < C_DIM){
        float rsum = 0.f;
#pragma unroll
        for (int j2 = 0; j2 < 8; ++j2) rsum += ps[j2][t];
        out[((size_t)b * K_DIM + k) * C_DIM + t] = rsum - wsl * cw[k * C_DIM + t];
    }
}

extern "C" void kernel_launch(void* const* d_in, const int* in_sizes, int n_in,
                              void* d_out, int out_size, void* d_ws, size_t ws_size,
                              hipStream_t stream){
    (void)in_sizes; (void)n_in; (void)out_size; (void)ws_size;
    const float* x     = (const float*)d_in[0];
    const float* cw    = (const float*)d_in[1];
    const float* scale = (const float*)d_in[2];
    float* out = (float*)d_out;

    // workspace carve
    char* p = (char*)d_ws;
    unsigned short* wxp = (unsigned short*)p;
    p += (size_t)32 * NBP * K_DIM * C_DIM * sizeof(unsigned short);   // 16.8 MB
    float* wsp = (float*)p;                                           // 32*NBP*K*4 = 262 KB

    enc_main<<<dim3(NBP, 32), 128, 0, stream>>>(x, cw, scale, wxp, wsp);
    enc_reduce<<<32 * K_DIM, 256, 0, stream>>>(wxp, wsp, cw, out);
}

// Round 16
// 69.270 us; speedup vs baseline: 1.0333x; 1.0333x over previous
//
#include <hip/hip_runtime.h>

#define N_SP 16384
#define C_DIM 128
#define K_DIM 32
#define TILEN 32
#define NBP   128    // partial blocks per batch; each does 4 tiles (128*128 = 16384)

typedef short short8 __attribute__((ext_vector_type(8)));
typedef float f32x16 __attribute__((ext_vector_type(16)));

__device__ __forceinline__ unsigned f2bfu(float f){
    return (__float_as_uint(f) + 0x8000u) >> 16;   // cheap RN to bf16 bits
}
__device__ __forceinline__ unsigned short f2bf(float f){
    return (unsigned short)f2bfu(f);
}
__device__ __forceinline__ float bf2f(unsigned u){
    return __uint_as_float(u << 16);
}

// XOR-swizzled index into a [row][32] ushort tile: flips n bits 3..4 by row&3
// -> 8-u16 (16B) chunks stay contiguous & aligned; rows spread across banks
#define SWZ(row, n) (((row) << 5) + ((n) ^ (((row) & 3) << 3)))

union FragU { int i[4]; short8 s; };

__global__ __launch_bounds__(64) void enc_main(
    const float* __restrict__ x,       // [B][C][N]
    const float* __restrict__ cw,      // [K][C] fp32
    const float* __restrict__ scale,   // [K]
    unsigned short* __restrict__ wxp,  // [32*NBP][K][C] bf16 block partials
    float* __restrict__ wsp)           // [32*NBP][K]    fp32 block partials
{
    __shared__ unsigned short xs[C_DIM * TILEN];   // bf16 x[c][n'] swizzled (8 KB)
    __shared__ unsigned short aws[K_DIM * TILEN];  // bf16 aw[k][n'] (2 KB); prologue
                                                   // aliases first 256B as combo[64] f32
    const int t   = threadIdx.x;   // one wave; thread owns (col l31, c-half hi*64..+63)
    const int r   = blockIdx.x;    // 0..NBP-1
    const int b   = blockIdx.y;
    const int hi  = t >> 5;
    const int l31 = t & 31;

    const int nbase = r * 128;     // uniform: 4 tiles of 32 per block

    const float* xb = x + (size_t)b * C_DIM * N_SP + (size_t)(hi * 64) * N_SP;

    // ---- prologue: self-compute cwA, combo (no prep kernel) ----
    const float s_k = scale[l31];
    const float m2s = -2.f * s_k;
    float c2p = 0.f;
    short8 cwA[8];
#pragma unroll
    for (int ksg = 0; ksg < 8; ++ksg){
        const float* cp = cw + l31 * C_DIM + ksg * 16 + hi * 8;
        float4 a  = *(const float4*)cp;
        float4 b4 = *(const float4*)(cp + 4);
        c2p = fmaf(a.x, a.x, c2p);  c2p = fmaf(a.y, a.y, c2p);
        c2p = fmaf(a.z, a.z, c2p);  c2p = fmaf(a.w, a.w, c2p);
        c2p = fmaf(b4.x, b4.x, c2p); c2p = fmaf(b4.y, b4.y, c2p);
        c2p = fmaf(b4.z, b4.z, c2p); c2p = fmaf(b4.w, b4.w, c2p);
        FragU f;
        f.i[0] = (int)(f2bfu(m2s * a.x)  | (f2bfu(m2s * a.y)  << 16));
        f.i[1] = (int)(f2bfu(m2s * a.z)  | (f2bfu(m2s * a.w)  << 16));
        f.i[2] = (int)(f2bfu(m2s * b4.x) | (f2bfu(m2s * b4.y) << 16));
        f.i[3] = (int)(f2bfu(m2s * b4.z) | (f2bfu(m2s * b4.w) << 16));
        cwA[ksg] = f.s;
    }
    const float c2 = c2p + __shfl_xor(c2p, 32);   // full ||cw_k||^2, k = l31

    {   // combo broadcast through LDS (aliased into aws; single wave -> no barrier)
        float* combof = (float*)aws;
        combof[2 * l31]     = s_k;          // duplicate write from hi=0/1: same value
        combof[2 * l31 + 1] = s_k * c2;
    }
    float csx[16], csy[16];
#pragma unroll
    for (int q = 0; q < 16; ++q){
        const int row = (q & 3) + 8 * (q >> 2) + 4 * hi;
        const float* combof = (const float*)aws;
        csx[q] = combof[2 * row];
        csy[q] = combof[2 * row + 1];
    }

    f32x16 acc0, acc1, acc2, acc3, accS;
#pragma unroll
    for (int i = 0; i < 16; ++i){
        acc0[i]=0.f; acc1[i]=0.f; acc2[i]=0.f; acc3[i]=0.f; accS[i]=0.f;
    }
    short8 ones;
#pragma unroll
    for (int i = 0; i < 8; ++i) ones[i] = (short)0x3F80;  // bf16 1.0

#pragma unroll 1
    for (int tile = 0; tile < 4; ++tile){
        const int n0 = nbase + tile * TILEN;
        const float* xp = xb + n0 + l31;

        __syncthreads();   // xs/aws safe to overwrite (prev tile's phase-D done)

        f32x16 sA;         // S[k][n] accumulator, cols n = l31
#pragma unroll
        for (int i = 0; i < 16; ++i) sA[i] = 0.f;

        float x2 = 0.f;    // partial ||x||^2 over this thread's 64 c-rows
        int xr[32];        // packed bf16 pairs: xr[m] = rows 2m,2m+1 (local)

        // ---- phase 1: stream 64 c-rows (depth-2, 8-wide), stage bf16 ----
        float cur[8], nx1[8];
#pragma unroll
        for (int j = 0; j < 8; ++j) cur[j] = xp[(size_t)j * N_SP];
#pragma unroll
        for (int j = 0; j < 8; ++j) nx1[j] = xp[(size_t)(8 + j) * N_SP];

#pragma unroll
        for (int g = 0; g < 8; ++g){
            float nx2[8];
            if (g < 6){
#pragma unroll
                for (int j = 0; j < 8; ++j) nx2[j] = xp[(size_t)((g + 2) * 8 + j) * N_SP];
            } else {
#pragma unroll
                for (int j = 0; j < 8; ++j) nx2[j] = 0.f;
            }
#pragma unroll
            for (int j = 0; j < 8; j += 2){
                const int rl = g * 8 + j;        // local row 0..63
                const int c  = hi * 64 + rl;     // global c-row
                const float a0 = cur[j], a1 = cur[j + 1];
                x2 = fmaf(a0, a0, x2);
                x2 = fmaf(a1, a1, x2);
                const unsigned u0 = f2bfu(a0), u1 = f2bfu(a1);
                xs[SWZ(c,     l31)] = (unsigned short)u0;
                xs[SWZ(c + 1, l31)] = (unsigned short)u1;
                xr[rl >> 1] = (int)(u0 | (u1 << 16));
            }
            if (g < 7){
#pragma unroll
                for (int j = 0; j < 8; ++j){ cur[j] = nx1[j]; nx1[j] = nx2[j]; }
            }
        }

        // ---- phase S: S[k][col l31] += cwt2[k][c] * x[c][col], 8 c-steps of 16 ----
        // pair (t, t^32) holds same column, different c-half; exchange via shfl_xor
#pragma unroll
        for (int ks = 0; ks < 8; ++ks){
            FragU f;
            if (ks < 4){
#pragma unroll
                for (int d = 0; d < 4; ++d){
                    const int own = xr[ks * 8 + d];                     // c = ks*16+2d (hi=0)
                    const int oth = __shfl_xor(xr[ks * 8 + 4 + d], 32); // c = ks*16+8+2d
                    f.i[d] = hi ? oth : own;
                }
            } else {
                const int k4 = ks - 4;
#pragma unroll
                for (int d = 0; d < 4; ++d){
                    const int own = xr[k4 * 8 + 4 + d];                 // c = ks*16+8+2d (hi=1)
                    const int oth = __shfl_xor(xr[k4 * 8 + d], 32);     // c = ks*16+2d
                    f.i[d] = hi ? own : oth;
                }
            }
            sA = __builtin_amdgcn_mfma_f32_32x32x16_bf16(cwA[ks], f.s, sA, 0, 0, 0);
        }

        // ---- phase 2: softmax over k (col l31), D-layout ----
        const float x2f = x2 + __shfl_xor(x2, 32);   // full ||x||^2 for col l31
        {
            float arg[16]; float ml = -3.4e38f;
#pragma unroll
            for (int q = 0; q < 16; ++q){
                arg[q] = fmaf(csx[q], x2f, sA[q] + csy[q]);  // scale*(x2-2x.cw+c2)
                ml = fmaxf(ml, arg[q]);
            }
            const float mm = fmaxf(ml, __shfl_xor(ml, 32));
            float sum = 0.f;
#pragma unroll
            for (int q = 0; q < 16; ++q){ float p = __expf(arg[q] - mm); arg[q] = p; sum += p; }
            sum += __shfl_xor(sum, 32);
            const float rr = 1.f / sum;
#pragma unroll
            for (int q = 0; q < 16; ++q){
                const int row = (q & 3) + 8 * (q >> 2) + 4 * hi;
                aws[SWZ(row, l31)] = f2bf(arg[q] * rr);
            }
        }

        __syncthreads();   // aws complete

        // ---- phase D: wx[k][c] += aw[k][n] * x[n][c], 2 n-steps of 16 ----
#pragma unroll
        for (int ks = 0; ks < 2; ++ks){
            const int n8 = ks * 16 + hi * 8;
            short8 af  = *(const short8*)(const void*)&aws[SWZ(l31, n8)];
            short8 bf0 = *(const short8*)(const void*)&xs[SWZ(l31,      n8)];
            short8 bf1 = *(const short8*)(const void*)&xs[SWZ(32 + l31, n8)];
            short8 bf2 = *(const short8*)(const void*)&xs[SWZ(64 + l31, n8)];
            short8 bf3 = *(const short8*)(const void*)&xs[SWZ(96 + l31, n8)];
            acc0 = __builtin_amdgcn_mfma_f32_32x32x16_bf16(af, bf0, acc0, 0, 0, 0);
            acc1 = __builtin_amdgcn_mfma_f32_32x32x16_bf16(af, bf1, acc1, 0, 0, 0);
            acc2 = __builtin_amdgcn_mfma_f32_32x32x16_bf16(af, bf2, acc2, 0, 0, 0);
            acc3 = __builtin_amdgcn_mfma_f32_32x32x16_bf16(af, bf3, acc3, 0, 0, 0);
            accS = __builtin_amdgcn_mfma_f32_32x32x16_bf16(af, ones, accS, 0, 0, 0);
        }
    }

    // ---- epilogue: block-private bf16 partial stores (no atomics) ----
    const int blk = b * NBP + r;
    unsigned short* wxp_blk = wxp + (size_t)blk * (K_DIM * C_DIM);
#pragma unroll
    for (int rg = 0; rg < 16; ++rg){
        const int row = (rg & 3) + 8 * (rg >> 2) + 4 * hi;  // verified D layout
        wxp_blk[row * C_DIM +      l31] = f2bf(acc0[rg]);
        wxp_blk[row * C_DIM + 32 + l31] = f2bf(acc1[rg]);
        wxp_blk[row * C_DIM + 64 + l31] = f2bf(acc2[rg]);
        wxp_blk[row * C_DIM + 96 + l31] = f2bf(acc3[rg]);
    }
    if (l31 == 0){
        float* wsp_blk = wsp + (size_t)blk * K_DIM;
#pragma unroll
        for (int rg = 0; rg < 16; ++rg){
            const int row = (rg & 3) + 8 * (rg >> 2) + 4 * hi;
            wsp_blk[row] = accS[rg];
        }
    }
}

// out[b][k][c] = sum_j wxp[b*NBP+j][k][c] - (sum_j wsp[b*NBP+j][k]) * cw[k][c]
__global__ __launch_bounds__(256) void enc_reduce(
    const unsigned short* __restrict__ wxp, const float* __restrict__ wsp,
    const float* __restrict__ cw, float* __restrict__ out)
{
    const int t = threadIdx.x;          // 0..255
    const int k = blockIdx.x & (K_DIM - 1);
    const int b = blockIdx.x >> 5;      // grid = 32*32

    __shared__ float ps[8][C_DIM];
    __shared__ float wsl[4];

    // wsum: threads 0..NBP-1 load one partial each (waves 0,1), wave-reduce
    float wv = (t < NBP) ? wsp[(size_t)(b * NBP + t) * K_DIM + k] : 0.f;
#pragma unroll
    for (int off = 32; off; off >>= 1) wv += __shfl_down(wv, off);
    if ((t & 63) == 0) wsl[t >> 6] = wv;

    // wx: thread (jg = t>>5, c4 = (t&31)*4) sums NBP/8 = 16 bf16x4 partials
    const int c4 = (t & 31) * 4;
    const int jg = t >> 5;              // 0..7
    float4 s; s.x = 0.f; s.y = 0.f; s.z = 0.f; s.w = 0.f;
    const unsigned short* pp = wxp + ((size_t)(b * NBP) + jg) * (K_DIM * C_DIM) + k * C_DIM + c4;
#pragma unroll
    for (int j = 0; j < NBP; j += 8){   // 16 iterations
        uint2 v = *(const uint2*)(pp + (size_t)j * (K_DIM * C_DIM));
        s.x += bf2f(v.x & 0xFFFFu);
        s.y += bf2f(v.x >> 16);
        s.z += bf2f(v.y & 0xFFFFu);
        s.w += bf2f(v.y >> 16);
    }
    *(float4*)&ps[jg][c4] = s;
    __syncthreads();

    if (t < C_DIM){
        const float wsh = wsl[0] + wsl[1];
        float rsum = 0.f;
#pragma unroll
        for (int j2 = 0; j2 < 8; ++j2) rsum += ps[j2][t];
        out[((size_t)b * K_DIM + k) * C_DIM + t] = rsum - wsh * cw[k * C_DIM + t];
    }
}

extern "C" void kernel_launch(void* const* d_in, const int* in_sizes, int n_in,
                              void* d_out, int out_size, void* d_ws, size_t ws_size,
                              hipStream_t stream){
    (void)in_sizes; (void)n_in; (void)out_size; (void)ws_size;
    const float* x     = (const float*)d_in[0];
    const float* cw    = (const float*)d_in[1];
    const float* scale = (const float*)d_in[2];
    float* out = (float*)d_out;

    // workspace carve
    char* p = (char*)d_ws;
    unsigned short* wxp = (unsigned short*)p;
    p += (size_t)32 * NBP * K_DIM * C_DIM * sizeof(unsigned short);   // 33.6 MB
    float* wsp = (float*)p;                                           // 32*NBP*K*4 = 524 KB

    enc_main<<<dim3(NBP, 32), 64, 0, stream>>>(x, cw, scale, wxp, wsp);
    enc_reduce<<<32 * K_DIM, 256, 0, stream>>>(wxp, wsp, cw, out);
}